// Round 1
// baseline (1747.399 us; speedup 1.0000x reference)
//
#include <hip/hip_runtime.h>
#include <math.h>

#define N_NODES 50000
#define N_EDGES 800000
#define EP      (N_EDGES + N_NODES)   // 850000 edges incl self-loops
#define G_GRAPHS 256
#define BN_EPS   1e-5f
#define NEG_SLOPE 0.2f

static __device__ __forceinline__ float lrelu(float x) {
    return x > 0.f ? x : NEG_SLOPE * x;
}

// ---------------------------------------------------------------- CSR build
__global__ void k_hist(const int* __restrict__ ei, int* __restrict__ deg) {
    int stride = gridDim.x * blockDim.x;
    for (int e = blockIdx.x * blockDim.x + threadIdx.x; e < EP; e += stride) {
        int d = (e < N_EDGES) ? ei[N_EDGES + e] : (e - N_EDGES);
        atomicAdd(&deg[d], 1);
    }
}

__global__ void k_scan1(const int* __restrict__ deg, int* __restrict__ row_start,
                        int* __restrict__ totals) {
    __shared__ int buf[1024];
    int t = threadIdx.x;
    int i = blockIdx.x * 1024 + t;
    int v = (i < N_NODES) ? deg[i] : 0;
    buf[t] = v;
    __syncthreads();
    for (int off = 1; off < 1024; off <<= 1) {
        int add = (t >= off) ? buf[t - off] : 0;
        __syncthreads();
        buf[t] += add;
        __syncthreads();
    }
    if (i < N_NODES) row_start[i] = buf[t] - v;     // exclusive
    if (t == 1023) totals[blockIdx.x] = buf[t];
}

__global__ void k_scan2(int* __restrict__ totals, int nb) {
    if (threadIdx.x == 0 && blockIdx.x == 0) {
        int run = 0;
        for (int i = 0; i < nb; ++i) { int v = totals[i]; totals[i] = run; run += v; }
    }
}

__global__ void k_scan3(int* __restrict__ row_start, const int* __restrict__ totals) {
    int i = blockIdx.x * blockDim.x + threadIdx.x;
    if (i < N_NODES) row_start[i] += totals[i >> 10];
    if (i == 0) row_start[N_NODES] = EP;
}

__global__ void k_scatter(const int* __restrict__ ei, const int* __restrict__ row_start,
                          int* __restrict__ cursor, int* __restrict__ csr_src) {
    int stride = gridDim.x * blockDim.x;
    for (int e = blockIdx.x * blockDim.x + threadIdx.x; e < EP; e += stride) {
        int s, d;
        if (e < N_EDGES) { s = ei[e]; d = ei[N_EDGES + e]; }
        else             { s = d = e - N_EDGES; }
        int pos = row_start[d] + atomicAdd(&cursor[d], 1);
        csr_src[pos] = s;
    }
}

// ---------------------------------------------------------------- GEMM (fp32, 64x64x16 tile)
__launch_bounds__(256)
__global__ void k_gemm(const float* __restrict__ A, const float* __restrict__ B,
                       float* __restrict__ C, int M, int K, int Nc) {
    __shared__ float AsT[16][64];
    __shared__ float Bs[16][64];
    int tid = threadIdx.x;
    int r0 = blockIdx.x * 64;
    int c0 = blockIdx.y * 64;
    int tx = tid & 15, ty = tid >> 4;
    float acc[4][4] = {};

    int ar = r0 + (tid >> 2);
    int ak = (tid & 3) * 4;
    int bk = tid >> 4;
    int bc = (tid & 15) * 4;

    for (int k0 = 0; k0 < K; k0 += 16) {
        float4 av = make_float4(0.f, 0.f, 0.f, 0.f);
        if (ar < M) av = *(const float4*)&A[(size_t)ar * K + k0 + ak];
        AsT[ak + 0][tid >> 2] = av.x;
        AsT[ak + 1][tid >> 2] = av.y;
        AsT[ak + 2][tid >> 2] = av.z;
        AsT[ak + 3][tid >> 2] = av.w;
        float4 bv = *(const float4*)&B[(size_t)(k0 + bk) * Nc + c0 + bc];
        *(float4*)&Bs[bk][bc] = bv;
        __syncthreads();
        #pragma unroll
        for (int kk = 0; kk < 16; ++kk) {
            float4 a4 = *(float4*)&AsT[kk][ty * 4];
            float4 b4 = *(float4*)&Bs[kk][tx * 4];
            float a[4] = {a4.x, a4.y, a4.z, a4.w};
            float b[4] = {b4.x, b4.y, b4.z, b4.w};
            #pragma unroll
            for (int i = 0; i < 4; ++i)
                #pragma unroll
                for (int j = 0; j < 4; ++j)
                    acc[i][j] += a[i] * b[j];
        }
        __syncthreads();
    }
    #pragma unroll
    for (int i = 0; i < 4; ++i) {
        int r = r0 + ty * 4 + i;
        if (r < M)
            *(float4*)&C[(size_t)r * Nc + c0 + tx * 4] =
                make_float4(acc[i][0], acc[i][1], acc[i][2], acc[i][3]);
    }
}

// ---------------------------------------------------------------- attention scores s_src/s_dst
template<int H>
__global__ void k_scores(const float* __restrict__ hb, const float* __restrict__ asr,
                         const float* __restrict__ adr, float* __restrict__ s_src,
                         float* __restrict__ s_dst) {
    const int W = H * 128;
    int n = blockIdx.x;
    int t = threadIdx.x;    // 128 threads
    __shared__ float red_s[2], red_d[2];
    for (int head = 0; head < H; ++head) {
        float v  = hb[(size_t)n * W + head * 128 + t];
        float ps = v * asr[head * 128 + t];
        float pd = v * adr[head * 128 + t];
        #pragma unroll
        for (int off = 32; off > 0; off >>= 1) {
            ps += __shfl_down(ps, off, 64);
            pd += __shfl_down(pd, off, 64);
        }
        if ((t & 63) == 0) { red_s[t >> 6] = ps; red_d[t >> 6] = pd; }
        __syncthreads();
        if (t == 0)       s_src[n * H + head] = red_s[0] + red_s[1];
        else if (t == 64) s_dst[n * H + head] = red_d[0] + red_d[1];
        __syncthreads();
    }
}

// ---------------------------------------------------------------- per-dst softmax over incoming edges
template<int H>
__global__ void k_attn(const float* __restrict__ s_src, const float* __restrict__ s_dst,
                       const int* __restrict__ row_start, const int* __restrict__ csr,
                       float* __restrict__ alpha) {
    int n = blockIdx.x;
    int lane = threadIdx.x;           // 64
    const int EPI = 64 / H;
    int head = lane % H;
    int eo   = lane / H;
    int lo = row_start[n], hi = row_start[n + 1];
    float sd = s_dst[n * H + head];

    float mx = -INFINITY;
    for (int p = lo + eo; p < hi; p += EPI) {
        int s = csr[p];
        float e = lrelu(s_src[s * H + head] + sd);
        alpha[(size_t)p * H + head] = e;
        mx = fmaxf(mx, e);
    }
    #pragma unroll
    for (int off = H; off < 64; off <<= 1) mx = fmaxf(mx, __shfl_xor(mx, off, 64));

    float sum = 0.f;
    for (int p = lo + eo; p < hi; p += EPI) {
        float ex = expf(alpha[(size_t)p * H + head] - mx);
        alpha[(size_t)p * H + head] = ex;
        sum += ex;
    }
    #pragma unroll
    for (int off = H; off < 64; off <<= 1) sum += __shfl_xor(sum, off, 64);

    float inv = 1.f / sum;
    for (int p = lo + eo; p < hi; p += EPI) alpha[(size_t)p * H + head] *= inv;
}

// ---------------------------------------------------------------- aggregation: out[n] = sum alpha*h[src] (+bias)
template<int H, int FPT>
__global__ void k_agg(const float* __restrict__ hb, const float* __restrict__ alpha,
                      const int* __restrict__ row_start, const int* __restrict__ csr,
                      const float* __restrict__ bias, float* __restrict__ out) {
    const int W  = H * 128;
    const int BT = W / FPT;           // blockDim.x
    int n = blockIdx.x;
    int t = threadIdx.x;
    int lo = row_start[n], hi = row_start[n + 1];
    float acc[FPT];
    int   fh[FPT];
    #pragma unroll
    for (int q = 0; q < FPT; ++q) { acc[q] = 0.f; fh[q] = (t + q * BT) >> 7; }
    for (int p = lo; p < hi; ++p) {
        int s = csr[p];
        const float* hrow = hb + (size_t)s * W;
        #pragma unroll
        for (int q = 0; q < FPT; ++q)
            acc[q] += alpha[(size_t)p * H + fh[q]] * hrow[t + q * BT];
    }
    #pragma unroll
    for (int q = 0; q < FPT; ++q) {
        int f = t + q * BT;
        out[(size_t)n * W + f] = acc[q] + bias[f];
    }
}

// ---------------------------------------------------------------- BatchNorm stats + apply+ELU
__global__ void k_bnstat(const float* __restrict__ x, float* __restrict__ bnsum,
                         float* __restrict__ bnsq, int W) {
    const int RPB = 64;
    int f  = threadIdx.x;             // W threads
    int r0 = blockIdx.x * RPB;
    int r1 = min(r0 + RPB, N_NODES);
    float s = 0.f, q = 0.f;
    for (int r = r0; r < r1; ++r) {
        float v = x[(size_t)r * W + f];
        s += v; q += v * v;
    }
    atomicAdd(&bnsum[f], s);
    atomicAdd(&bnsq[f], q);
}

__global__ void k_bnelu(float* __restrict__ x, const float* __restrict__ bnsum,
                        const float* __restrict__ bnsq, const float* __restrict__ gamma,
                        const float* __restrict__ beta, int W) {
    size_t total = (size_t)N_NODES * W;
    size_t i = (size_t)blockIdx.x * blockDim.x + threadIdx.x;
    if (i >= total) return;
    int f = (int)(i & (W - 1));       // W is 512 or 128 (pow2)
    const float invN = 1.f / (float)N_NODES;
    float mean = bnsum[f] * invN;
    float var  = bnsq[f] * invN - mean * mean;
    float y = gamma[f] * (x[i] - mean) * rsqrtf(var + BN_EPS) + beta[f];
    x[i] = y > 0.f ? y : expm1f(y);
}

// ---------------------------------------------------------------- global mean pool (batch_idx sorted)
__global__ void k_pool(const float* __restrict__ x, const int* __restrict__ batch,
                       float* __restrict__ out) {
    int g = blockIdx.x;               // 256
    int f = threadIdx.x;              // 128
    int a = 0, b = N_NODES;
    while (a < b) { int m = (a + b) >> 1; if (batch[m] < g) a = m + 1; else b = m; }
    int lo = a;
    b = N_NODES;
    while (a < b) { int m = (a + b) >> 1; if (batch[m] < g + 1) a = m + 1; else b = m; }
    int hi = a;
    float s = 0.f;
    for (int r = lo; r < hi; ++r) s += x[(size_t)r * 128 + f];
    int cnt = hi - lo;
    out[g * 128 + f] = s / (float)(cnt > 0 ? cnt : 1);
}

// ---------------------------------------------------------------- launch
extern "C" void kernel_launch(void* const* d_in, const int* in_sizes, int n_in,
                              void* d_out, int out_size, void* d_ws, size_t ws_size,
                              hipStream_t stream) {
    const float* x     = (const float*)d_in[0];
    const int*   ei    = (const int*)d_in[1];
    const int*   batch = (const int*)d_in[2];
    const float* Wm[3]  = {(const float*)d_in[3],  (const float*)d_in[9],  (const float*)d_in[15]};
    const float* asr[3] = {(const float*)d_in[4],  (const float*)d_in[10], (const float*)d_in[16]};
    const float* adr[3] = {(const float*)d_in[5],  (const float*)d_in[11], (const float*)d_in[17]};
    const float* bia[3] = {(const float*)d_in[6],  (const float*)d_in[12], (const float*)d_in[18]};
    const float* gam[3] = {(const float*)d_in[7],  (const float*)d_in[13], (const float*)d_in[19]};
    const float* bet[3] = {(const float*)d_in[8],  (const float*)d_in[14], (const float*)d_in[20]};

    char* w = (char*)d_ws;
    auto alloc = [&](size_t bytes) -> void* {
        void* p = (void*)w;
        w += (bytes + 255) & ~(size_t)255;
        return p;
    };
    float* act   = (float*)alloc((size_t)N_NODES * 512 * 4);
    float* hb    = (float*)alloc((size_t)N_NODES * 512 * 4);
    float* alpha = (float*)alloc((size_t)EP * 4 * 4);
    int* csr_src   = (int*)alloc((size_t)EP * 4);
    int* row_start = (int*)alloc((size_t)(N_NODES + 1) * 4);
    int* deg       = (int*)alloc((size_t)N_NODES * 4);
    int* cursor    = (int*)alloc((size_t)N_NODES * 4);
    float* s_src = (float*)alloc((size_t)N_NODES * 4 * 4);
    float* s_dst = (float*)alloc((size_t)N_NODES * 4 * 4);
    float* bn    = (float*)alloc(1024 * 4);      // bnsum[512] + bnsq[512]
    int* totals  = (int*)alloc(64 * 4);

    // ---- CSR by dst (shared by all 3 layers)
    hipMemsetAsync(deg, 0, (size_t)N_NODES * 4, stream);
    hipMemsetAsync(cursor, 0, (size_t)N_NODES * 4, stream);
    k_hist<<<512, 256, 0, stream>>>(ei, deg);
    k_scan1<<<(N_NODES + 1023) / 1024, 1024, 0, stream>>>(deg, row_start, totals);
    k_scan2<<<1, 64, 0, stream>>>(totals, (N_NODES + 1023) / 1024);
    k_scan3<<<(N_NODES + 255) / 256, 256, 0, stream>>>(row_start, totals);
    k_scatter<<<512, 256, 0, stream>>>(ei, row_start, cursor, csr_src);

    auto layer = [&](const float* A, int K, int li, int H) {
        int Wd = H * 128;
        dim3 gg((N_NODES + 63) / 64, Wd / 64);
        k_gemm<<<gg, 256, 0, stream>>>(A, Wm[li], hb, N_NODES, K, Wd);
        if (H == 4) {
            k_scores<4><<<N_NODES, 128, 0, stream>>>(hb, asr[li], adr[li], s_src, s_dst);
            k_attn<4><<<N_NODES, 64, 0, stream>>>(s_src, s_dst, row_start, csr_src, alpha);
            k_agg<4, 2><<<N_NODES, 256, 0, stream>>>(hb, alpha, row_start, csr_src, bia[li], act);
        } else {
            k_scores<1><<<N_NODES, 128, 0, stream>>>(hb, asr[li], adr[li], s_src, s_dst);
            k_attn<1><<<N_NODES, 64, 0, stream>>>(s_src, s_dst, row_start, csr_src, alpha);
            k_agg<1, 1><<<N_NODES, 128, 0, stream>>>(hb, alpha, row_start, csr_src, bia[li], act);
        }
        hipMemsetAsync(bn, 0, 1024 * 4, stream);
        k_bnstat<<<(N_NODES + 63) / 64, Wd, 0, stream>>>(act, bn, bn + 512, Wd);
        size_t tot = (size_t)N_NODES * Wd;
        k_bnelu<<<(unsigned)((tot + 255) / 256), 256, 0, stream>>>(act, bn, bn + 512,
                                                                    gam[li], bet[li], Wd);
    };

    layer(x,   128, 0, 4);   // in -> act [N,512]
    layer(act, 512, 1, 4);   // act -> act [N,512]
    layer(act, 512, 2, 1);   // act -> act [N,128]

    k_pool<<<G_GRAPHS, 128, 0, stream>>>(act, batch, (float*)d_out);
}

// Round 2
// 1343.002 us; speedup vs baseline: 1.3011x; 1.3011x over previous
//
#include <hip/hip_runtime.h>
#include <math.h>
#include <stdint.h>

#define N_NODES 50000
#define N_EDGES 800000
#define EP      (N_EDGES + N_NODES)   // 850000 edges incl self-loops
#define G_GRAPHS 256
#define BN_EPS   1e-5f
#define NEG_SLOPE 0.2f

typedef short short8 __attribute__((ext_vector_type(8)));
typedef float f32x4 __attribute__((ext_vector_type(4)));
typedef unsigned short u16;

static __device__ __forceinline__ float lrelu(float x) {
    return x > 0.f ? x : NEG_SLOPE * x;
}

// bf16 round-to-nearest-even (hi part); lo = bf16(a - hi)
static __device__ __forceinline__ u16 bf16hi(float f) {
    unsigned u = __float_as_uint(f);
    u += 0x7FFFu + ((u >> 16) & 1u);
    return (u16)(u >> 16);
}
static __device__ __forceinline__ float bf2f(u16 h) {
    return __uint_as_float((unsigned)h << 16);
}

static __device__ __forceinline__ void gld_lds16(const void* g, void* l) {
    __builtin_amdgcn_global_load_lds((const __attribute__((address_space(1))) void*)g,
                                     (__attribute__((address_space(3))) void*)l, 16, 0, 0);
}

// ---------------------------------------------------------------- CSR build
__global__ void k_hist(const int* __restrict__ ei, int* __restrict__ deg) {
    int stride = gridDim.x * blockDim.x;
    for (int e = blockIdx.x * blockDim.x + threadIdx.x; e < EP; e += stride) {
        int d = (e < N_EDGES) ? ei[N_EDGES + e] : (e - N_EDGES);
        atomicAdd(&deg[d], 1);
    }
}

__global__ void k_scan1(const int* __restrict__ deg, int* __restrict__ row_start,
                        int* __restrict__ totals) {
    __shared__ int buf[1024];
    int t = threadIdx.x;
    int i = blockIdx.x * 1024 + t;
    int v = (i < N_NODES) ? deg[i] : 0;
    buf[t] = v;
    __syncthreads();
    for (int off = 1; off < 1024; off <<= 1) {
        int add = (t >= off) ? buf[t - off] : 0;
        __syncthreads();
        buf[t] += add;
        __syncthreads();
    }
    if (i < N_NODES) row_start[i] = buf[t] - v;     // exclusive
    if (t == 1023) totals[blockIdx.x] = buf[t];
}

__global__ void k_scan2(int* __restrict__ totals, int nb) {
    if (threadIdx.x == 0 && blockIdx.x == 0) {
        int run = 0;
        for (int i = 0; i < nb; ++i) { int v = totals[i]; totals[i] = run; run += v; }
    }
}

__global__ void k_scan3(int* __restrict__ row_start, const int* __restrict__ totals) {
    int i = blockIdx.x * blockDim.x + threadIdx.x;
    if (i < N_NODES) row_start[i] += totals[i >> 10];
    if (i == 0) row_start[N_NODES] = EP;
}

__global__ void k_scatter(const int* __restrict__ ei, const int* __restrict__ row_start,
                          int* __restrict__ cursor, int* __restrict__ csr_src) {
    int stride = gridDim.x * blockDim.x;
    for (int e = blockIdx.x * blockDim.x + threadIdx.x; e < EP; e += stride) {
        int s, d;
        if (e < N_EDGES) { s = ei[e]; d = ei[N_EDGES + e]; }
        else             { s = d = e - N_EDGES; }
        int pos = row_start[d] + atomicAdd(&cursor[d], 1);
        csr_src[pos] = s;
    }
}

// ---------------------------------------------------------------- weight convert:
// W [K,Nc] fp32 -> bthi/btlo bf16 in pre-swizzled chunk layout:
// chunk (c, ks) of 4096 elems laid out [kq][col][8] so that GEMM's linear
// global_load_lds staging lands it as LDS [4][128][8].
__global__ void k_cvtW(const float* __restrict__ W, u16* __restrict__ bthi,
                       u16* __restrict__ btlo, int Nc, int nsh, int KS) {
    int i = blockIdx.x * 256 + threadIdx.x;
    if (i >= (KS << 5) * Nc) return;
    int k = i >> nsh;
    int n = i & (Nc - 1);
    int c = n >> 7, col = n & 127;
    int ks = k >> 5, kq = (k >> 3) & 3, j = k & 7;
    size_t idx = ((size_t)(c * KS + ks)) * 4096 + kq * 1024 + col * 8 + j;
    float v = W[i];
    u16 h = bf16hi(v);
    bthi[idx] = h;
    btlo[idx] = bf16hi(v - bf2f(h));
}

// ---------------------------------------------------------------- split-bf16 MFMA GEMM
// C[M,Nc] = A[M,K] (fp32, split on the fly) x B (pre-split bf16, B^T chunks)
// 128x128 tile, BK=32, 4 waves, 3 MFMA passes (hi*hi + hi*lo + lo*hi).
__launch_bounds__(256)
__global__ void k_gemm_mfma(const float* __restrict__ A, const u16* __restrict__ bthi,
                            const u16* __restrict__ btlo, float* __restrict__ C,
                            int M, int K, int Nc) {
    __shared__ u16 Ah[4096], Al[4096], Bh[4096], Bl[4096];   // each [4][128][8]
    const int t    = threadIdx.x;
    const int lane = t & 63, wv = t >> 6;
    const int wr = wv >> 1, wc = wv & 1;         // wave quadrant (2x2 of 64x64)
    const int lr = lane & 15, kq = lane >> 4;
    const int r0 = blockIdx.x * 128, c0 = blockIdx.y * 128;
    const int KS = K >> 5;

    // A staging role: thread -> (row 0..127, 16-float half)
    const int ar = t >> 1;
    const int ahf = t & 1;
    const int garow = r0 + ar;
    const bool avalid = garow < M;
    const float* arow = A + (size_t)garow * K + ahf * 16;

    const size_t bchunk0 = (size_t)blockIdx.y * KS * 4096;

    f32x4 acc[4][4];
    #pragma unroll
    for (int m = 0; m < 4; ++m)
        #pragma unroll
        for (int n = 0; n < 4; ++n) {
            acc[m][n][0] = 0.f; acc[m][n][1] = 0.f;
            acc[m][n][2] = 0.f; acc[m][n][3] = 0.f;
        }

    for (int ks = 0; ks < KS; ++ks) {
        // ---- issue A global loads (overlaps prior MFMA)
        float4 av[4];
        const float4* ap = (const float4*)(arow + ks * 32);
        if (avalid) {
            av[0] = ap[0]; av[1] = ap[1]; av[2] = ap[2]; av[3] = ap[3];
        } else {
            av[0] = av[1] = av[2] = av[3] = make_float4(0.f, 0.f, 0.f, 0.f);
        }
        __syncthreads();   // previous iteration's LDS reads complete

        // ---- split + ds_write A into [4][128][8]
        float f[16];
        f[0]=av[0].x; f[1]=av[0].y; f[2]=av[0].z; f[3]=av[0].w;
        f[4]=av[1].x; f[5]=av[1].y; f[6]=av[1].z; f[7]=av[1].w;
        f[8]=av[2].x; f[9]=av[2].y; f[10]=av[2].z; f[11]=av[2].w;
        f[12]=av[3].x; f[13]=av[3].y; f[14]=av[3].z; f[15]=av[3].w;
        u16 hi[16], lo[16];
        #pragma unroll
        for (int i = 0; i < 16; ++i) {
            hi[i] = bf16hi(f[i]);
            lo[i] = bf16hi(f[i] - bf2f(hi[i]));
        }
        #pragma unroll
        for (int q = 0; q < 2; ++q) {
            int kqi = ahf * 2 + q;
            int off = kqi * 1024 + ar * 8;
            int4 wh, wl;
            wh.x = (unsigned)hi[q*8+0] | ((unsigned)hi[q*8+1] << 16);
            wh.y = (unsigned)hi[q*8+2] | ((unsigned)hi[q*8+3] << 16);
            wh.z = (unsigned)hi[q*8+4] | ((unsigned)hi[q*8+5] << 16);
            wh.w = (unsigned)hi[q*8+6] | ((unsigned)hi[q*8+7] << 16);
            wl.x = (unsigned)lo[q*8+0] | ((unsigned)lo[q*8+1] << 16);
            wl.y = (unsigned)lo[q*8+2] | ((unsigned)lo[q*8+3] << 16);
            wl.z = (unsigned)lo[q*8+4] | ((unsigned)lo[q*8+5] << 16);
            wl.w = (unsigned)lo[q*8+6] | ((unsigned)lo[q*8+7] << 16);
            *(int4*)&Ah[off] = wh;
            *(int4*)&Al[off] = wl;
        }

        // ---- B via global_load_lds (linear; global layout pre-swizzled)
        const u16* bhs = bthi + bchunk0 + (size_t)ks * 4096;
        const u16* bls = btlo + bchunk0 + (size_t)ks * 4096;
        #pragma unroll
        for (int p = 0; p < 2; ++p) {
            int ge = p * 2048 + wv * 512 + lane * 8;   // per-lane global elem
            int le = p * 2048 + wv * 512;              // wave-uniform LDS elem
            gld_lds16(bhs + ge, &Bh[le]);
            gld_lds16(bls + ge, &Bl[le]);
        }
        __syncthreads();   // ds_writes visible + gload_lds drained

        // ---- fragments + 48 MFMAs
        short8 afh[4], afl[4], bfh[4], bfl[4];
        #pragma unroll
        for (int m = 0; m < 4; ++m) {
            int row = wr * 64 + m * 16 + lr;
            int off = kq * 1024 + row * 8;
            afh[m] = *(const short8*)&Ah[off];
            afl[m] = *(const short8*)&Al[off];
        }
        #pragma unroll
        for (int n = 0; n < 4; ++n) {
            int col = wc * 64 + n * 16 + lr;
            int off = kq * 1024 + col * 8;
            bfh[n] = *(const short8*)&Bh[off];
            bfl[n] = *(const short8*)&Bl[off];
        }
        #pragma unroll
        for (int m = 0; m < 4; ++m)
            #pragma unroll
            for (int n = 0; n < 4; ++n) {
                acc[m][n] = __builtin_amdgcn_mfma_f32_16x16x32_bf16(afh[m], bfh[n], acc[m][n], 0, 0, 0);
                acc[m][n] = __builtin_amdgcn_mfma_f32_16x16x32_bf16(afh[m], bfl[n], acc[m][n], 0, 0, 0);
                acc[m][n] = __builtin_amdgcn_mfma_f32_16x16x32_bf16(afl[m], bfh[n], acc[m][n], 0, 0, 0);
            }
    }

    // ---- epilogue: C[row][col], col=lane&15, row=(lane>>4)*4+reg (m91-verified)
    #pragma unroll
    for (int m = 0; m < 4; ++m) {
        int rowb = r0 + wr * 64 + m * 16 + kq * 4;
        #pragma unroll
        for (int n = 0; n < 4; ++n) {
            int col = c0 + wc * 64 + n * 16 + lr;
            #pragma unroll
            for (int j = 0; j < 4; ++j) {
                int r = rowb + j;
                if (r < M) C[(size_t)r * Nc + col] = acc[m][n][j];
            }
        }
    }
}

// ---------------------------------------------------------------- attention scores s_src/s_dst
template<int H>
__global__ void k_scores(const float* __restrict__ hb, const float* __restrict__ asr,
                         const float* __restrict__ adr, float* __restrict__ s_src,
                         float* __restrict__ s_dst) {
    const int W = H * 128;
    int n = blockIdx.x;
    int t = threadIdx.x;    // 128 threads
    __shared__ float red_s[2], red_d[2];
    for (int head = 0; head < H; ++head) {
        float v  = hb[(size_t)n * W + head * 128 + t];
        float ps = v * asr[head * 128 + t];
        float pd = v * adr[head * 128 + t];
        #pragma unroll
        for (int off = 32; off > 0; off >>= 1) {
            ps += __shfl_down(ps, off, 64);
            pd += __shfl_down(pd, off, 64);
        }
        if ((t & 63) == 0) { red_s[t >> 6] = ps; red_d[t >> 6] = pd; }
        __syncthreads();
        if (t == 0)       s_src[n * H + head] = red_s[0] + red_s[1];
        else if (t == 64) s_dst[n * H + head] = red_d[0] + red_d[1];
        __syncthreads();
    }
}

// ---------------------------------------------------------------- per-dst softmax over incoming edges
template<int H>
__global__ void k_attn(const float* __restrict__ s_src, const float* __restrict__ s_dst,
                       const int* __restrict__ row_start, const int* __restrict__ csr,
                       float* __restrict__ alpha) {
    int n = blockIdx.x;
    int lane = threadIdx.x;           // 64
    const int EPI = 64 / H;
    int head = lane % H;
    int eo   = lane / H;
    int lo = row_start[n], hi = row_start[n + 1];
    float sd = s_dst[n * H + head];

    float mx = -INFINITY;
    for (int p = lo + eo; p < hi; p += EPI) {
        int s = csr[p];
        float e = lrelu(s_src[s * H + head] + sd);
        alpha[(size_t)p * H + head] = e;
        mx = fmaxf(mx, e);
    }
    #pragma unroll
    for (int off = H; off < 64; off <<= 1) mx = fmaxf(mx, __shfl_xor(mx, off, 64));

    float sum = 0.f;
    for (int p = lo + eo; p < hi; p += EPI) {
        float ex = expf(alpha[(size_t)p * H + head] - mx);
        alpha[(size_t)p * H + head] = ex;
        sum += ex;
    }
    #pragma unroll
    for (int off = H; off < 64; off <<= 1) sum += __shfl_xor(sum, off, 64);

    float inv = 1.f / sum;
    for (int p = lo + eo; p < hi; p += EPI) alpha[(size_t)p * H + head] *= inv;
}

// ---------------------------------------------------------------- aggregation: out[n] = sum alpha*h[src] (+bias)
template<int H, int FPT>
__global__ void k_agg(const float* __restrict__ hb, const float* __restrict__ alpha,
                      const int* __restrict__ row_start, const int* __restrict__ csr,
                      const float* __restrict__ bias, float* __restrict__ out) {
    const int W  = H * 128;
    const int BT = W / FPT;           // blockDim.x
    int n = blockIdx.x;
    int t = threadIdx.x;
    int lo = row_start[n], hi = row_start[n + 1];
    float acc[FPT];
    int   fh[FPT];
    #pragma unroll
    for (int q = 0; q < FPT; ++q) { acc[q] = 0.f; fh[q] = (t + q * BT) >> 7; }
    for (int p = lo; p < hi; ++p) {
        int s = csr[p];
        const float* hrow = hb + (size_t)s * W;
        #pragma unroll
        for (int q = 0; q < FPT; ++q)
            acc[q] += alpha[(size_t)p * H + fh[q]] * hrow[t + q * BT];
    }
    #pragma unroll
    for (int q = 0; q < FPT; ++q) {
        int f = t + q * BT;
        out[(size_t)n * W + f] = acc[q] + bias[f];
    }
}

// ---------------------------------------------------------------- BatchNorm stats + apply+ELU
__global__ void k_bnstat(const float* __restrict__ x, float* __restrict__ bnsum,
                         float* __restrict__ bnsq, int W) {
    const int RPB = 64;
    int f  = threadIdx.x;             // W threads
    int r0 = blockIdx.x * RPB;
    int r1 = min(r0 + RPB, N_NODES);
    float s = 0.f, q = 0.f;
    for (int r = r0; r < r1; ++r) {
        float v = x[(size_t)r * W + f];
        s += v; q += v * v;
    }
    atomicAdd(&bnsum[f], s);
    atomicAdd(&bnsq[f], q);
}

__global__ void k_bnelu(float* __restrict__ x, const float* __restrict__ bnsum,
                        const float* __restrict__ bnsq, const float* __restrict__ gamma,
                        const float* __restrict__ beta, int W) {
    size_t total = (size_t)N_NODES * W;
    size_t i = (size_t)blockIdx.x * blockDim.x + threadIdx.x;
    if (i >= total) return;
    int f = (int)(i & (W - 1));       // W is 512 or 128 (pow2)
    const float invN = 1.f / (float)N_NODES;
    float mean = bnsum[f] * invN;
    float var  = bnsq[f] * invN - mean * mean;
    float y = gamma[f] * (x[i] - mean) * rsqrtf(var + BN_EPS) + beta[f];
    x[i] = y > 0.f ? y : expm1f(y);
}

// ---------------------------------------------------------------- global mean pool (batch_idx sorted)
__global__ void k_pool(const float* __restrict__ x, const int* __restrict__ batch,
                       float* __restrict__ out) {
    int g = blockIdx.x;               // 256
    int f = threadIdx.x;              // 128
    int a = 0, b = N_NODES;
    while (a < b) { int m = (a + b) >> 1; if (batch[m] < g) a = m + 1; else b = m; }
    int lo = a;
    b = N_NODES;
    while (a < b) { int m = (a + b) >> 1; if (batch[m] < g + 1) a = m + 1; else b = m; }
    int hi = a;
    float s = 0.f;
    for (int r = lo; r < hi; ++r) s += x[(size_t)r * 128 + f];
    int cnt = hi - lo;
    out[g * 128 + f] = s / (float)(cnt > 0 ? cnt : 1);
}

// ---------------------------------------------------------------- launch
extern "C" void kernel_launch(void* const* d_in, const int* in_sizes, int n_in,
                              void* d_out, int out_size, void* d_ws, size_t ws_size,
                              hipStream_t stream) {
    const float* x     = (const float*)d_in[0];
    const int*   ei    = (const int*)d_in[1];
    const int*   batch = (const int*)d_in[2];
    const float* Wm[3]  = {(const float*)d_in[3],  (const float*)d_in[9],  (const float*)d_in[15]};
    const float* asr[3] = {(const float*)d_in[4],  (const float*)d_in[10], (const float*)d_in[16]};
    const float* adr[3] = {(const float*)d_in[5],  (const float*)d_in[11], (const float*)d_in[17]};
    const float* bia[3] = {(const float*)d_in[6],  (const float*)d_in[12], (const float*)d_in[18]};
    const float* gam[3] = {(const float*)d_in[7],  (const float*)d_in[13], (const float*)d_in[19]};
    const float* bet[3] = {(const float*)d_in[8],  (const float*)d_in[14], (const float*)d_in[20]};

    char* w = (char*)d_ws;
    auto alloc = [&](size_t bytes) -> void* {
        void* p = (void*)w;
        w += (bytes + 255) & ~(size_t)255;
        return p;
    };
    float* act   = (float*)alloc((size_t)N_NODES * 512 * 4);
    float* hb    = (float*)alloc((size_t)N_NODES * 512 * 4);
    float* alpha = (float*)alloc((size_t)EP * 4 * 4);
    int* csr_src   = (int*)alloc((size_t)EP * 4);
    int* row_start = (int*)alloc((size_t)(N_NODES + 1) * 4);
    int* deg       = (int*)alloc((size_t)N_NODES * 4);
    int* cursor    = (int*)alloc((size_t)N_NODES * 4);
    float* s_src = (float*)alloc((size_t)N_NODES * 4 * 4);
    float* s_dst = (float*)alloc((size_t)N_NODES * 4 * 4);
    float* bn    = (float*)alloc(1024 * 4);      // bnsum[512] + bnsq[512]
    int* totals  = (int*)alloc(64 * 4);
    u16* bthi = (u16*)alloc((size_t)512 * 512 * 2);
    u16* btlo = (u16*)alloc((size_t)512 * 512 * 2);

    // ---- CSR by dst (shared by all 3 layers)
    hipMemsetAsync(deg, 0, (size_t)N_NODES * 4, stream);
    hipMemsetAsync(cursor, 0, (size_t)N_NODES * 4, stream);
    k_hist<<<512, 256, 0, stream>>>(ei, deg);
    k_scan1<<<(N_NODES + 1023) / 1024, 1024, 0, stream>>>(deg, row_start, totals);
    k_scan2<<<1, 64, 0, stream>>>(totals, (N_NODES + 1023) / 1024);
    k_scan3<<<(N_NODES + 255) / 256, 256, 0, stream>>>(row_start, totals);
    k_scatter<<<512, 256, 0, stream>>>(ei, row_start, cursor, csr_src);

    auto layer = [&](const float* Ain, int K, int li, int H) {
        int Wd = H * 128;
        int nsh = (Wd == 512) ? 9 : 7;
        int tot = K * Wd;
        k_cvtW<<<(tot + 255) / 256, 256, 0, stream>>>(Wm[li], bthi, btlo, Wd, nsh, K >> 5);
        dim3 gg((N_NODES + 127) / 128, Wd / 128);
        k_gemm_mfma<<<gg, 256, 0, stream>>>(Ain, bthi, btlo, hb, N_NODES, K, Wd);
        if (H == 4) {
            k_scores<4><<<N_NODES, 128, 0, stream>>>(hb, asr[li], adr[li], s_src, s_dst);
            k_attn<4><<<N_NODES, 64, 0, stream>>>(s_src, s_dst, row_start, csr_src, alpha);
            k_agg<4, 2><<<N_NODES, 256, 0, stream>>>(hb, alpha, row_start, csr_src, bia[li], act);
        } else {
            k_scores<1><<<N_NODES, 128, 0, stream>>>(hb, asr[li], adr[li], s_src, s_dst);
            k_attn<1><<<N_NODES, 64, 0, stream>>>(s_src, s_dst, row_start, csr_src, alpha);
            k_agg<1, 1><<<N_NODES, 128, 0, stream>>>(hb, alpha, row_start, csr_src, bia[li], act);
        }
        hipMemsetAsync(bn, 0, 1024 * 4, stream);
        k_bnstat<<<(N_NODES + 63) / 64, Wd, 0, stream>>>(act, bn, bn + 512, Wd);
        size_t tot2 = (size_t)N_NODES * Wd;
        k_bnelu<<<(unsigned)((tot2 + 255) / 256), 256, 0, stream>>>(act, bn, bn + 512,
                                                                    gam[li], bet[li], Wd);
    };

    layer(x,   128, 0, 4);   // in -> act [N,512]
    layer(act, 512, 1, 4);   // act -> act [N,512]
    layer(act, 512, 2, 1);   // act -> act [N,128]

    k_pool<<<G_GRAPHS, 128, 0, stream>>>(act, batch, (float*)d_out);
}

// Round 3
// 960.906 us; speedup vs baseline: 1.8185x; 1.3976x over previous
//
#include <hip/hip_runtime.h>
#include <math.h>
#include <stdint.h>

#define N_NODES 50000
#define N_EDGES 800000
#define EP      (N_EDGES + N_NODES)   // 850000 edges incl self-loops
#define G_GRAPHS 256
#define BN_EPS   1e-5f
#define NEG_SLOPE 0.2f

typedef short short8 __attribute__((ext_vector_type(8)));
typedef float f32x4 __attribute__((ext_vector_type(4)));
typedef unsigned short u16;

static __device__ __forceinline__ float lrelu(float x) {
    return x > 0.f ? x : NEG_SLOPE * x;
}

// bf16 round-to-nearest-even (hi part); lo = bf16(a - hi)
static __device__ __forceinline__ u16 bf16hi(float f) {
    unsigned u = __float_as_uint(f);
    u += 0x7FFFu + ((u >> 16) & 1u);
    return (u16)(u >> 16);
}
static __device__ __forceinline__ float bf2f(u16 h) {
    return __uint_as_float((unsigned)h << 16);
}

static __device__ __forceinline__ void gld_lds16(const void* g, void* l) {
    __builtin_amdgcn_global_load_lds((const __attribute__((address_space(1))) void*)g,
                                     (__attribute__((address_space(3))) void*)l, 16, 0, 0);
}

static __device__ __forceinline__ float2 h2f2(unsigned u) {
    union { unsigned u; _Float16 h[2]; } c;
    c.u = u;
    return make_float2((float)c.h[0], (float)c.h[1]);
}

// ---------------------------------------------------------------- CSR build
__global__ void k_hist(const int* __restrict__ ei, int* __restrict__ deg) {
    int stride = gridDim.x * blockDim.x;
    for (int e = blockIdx.x * blockDim.x + threadIdx.x; e < EP; e += stride) {
        int d = (e < N_EDGES) ? ei[N_EDGES + e] : (e - N_EDGES);
        atomicAdd(&deg[d], 1);
    }
}

__global__ void k_scan1(const int* __restrict__ deg, int* __restrict__ row_start,
                        int* __restrict__ totals) {
    __shared__ int buf[1024];
    int t = threadIdx.x;
    int i = blockIdx.x * 1024 + t;
    int v = (i < N_NODES) ? deg[i] : 0;
    buf[t] = v;
    __syncthreads();
    for (int off = 1; off < 1024; off <<= 1) {
        int add = (t >= off) ? buf[t - off] : 0;
        __syncthreads();
        buf[t] += add;
        __syncthreads();
    }
    if (i < N_NODES) row_start[i] = buf[t] - v;     // exclusive
    if (t == 1023) totals[blockIdx.x] = buf[t];
}

__global__ void k_scan2(int* __restrict__ totals, int nb) {
    if (threadIdx.x == 0 && blockIdx.x == 0) {
        int run = 0;
        for (int i = 0; i < nb; ++i) { int v = totals[i]; totals[i] = run; run += v; }
    }
}

__global__ void k_scan3(int* __restrict__ row_start, const int* __restrict__ totals) {
    int i = blockIdx.x * blockDim.x + threadIdx.x;
    if (i < N_NODES) row_start[i] += totals[i >> 10];
    if (i == 0) row_start[N_NODES] = EP;
}

__global__ void k_scatter(const int* __restrict__ ei, const int* __restrict__ row_start,
                          int* __restrict__ cursor, int* __restrict__ csr_src) {
    int stride = gridDim.x * blockDim.x;
    for (int e = blockIdx.x * blockDim.x + threadIdx.x; e < EP; e += stride) {
        int s, d;
        if (e < N_EDGES) { s = ei[e]; d = ei[N_EDGES + e]; }
        else             { s = d = e - N_EDGES; }
        int pos = row_start[d] + atomicAdd(&cursor[d], 1);
        csr_src[pos] = s;
    }
}

// ---------------------------------------------------------------- weight convert (pre-swizzled chunks)
__global__ void k_cvtW(const float* __restrict__ W, u16* __restrict__ bthi,
                       u16* __restrict__ btlo, int Nc, int nsh, int KS) {
    int i = blockIdx.x * 256 + threadIdx.x;
    if (i >= (KS << 5) * Nc) return;
    int k = i >> nsh;
    int n = i & (Nc - 1);
    int c = n >> 7, col = n & 127;
    int ks = k >> 5, kq = (k >> 3) & 3, j = k & 7;
    size_t idx = ((size_t)(c * KS + ks)) * 4096 + kq * 1024 + col * 8 + j;
    float v = W[i];
    u16 h = bf16hi(v);
    bthi[idx] = h;
    btlo[idx] = bf16hi(v - bf2f(h));
}

// ---------------------------------------------------------------- split-bf16 MFMA GEMM + fused epilogue:
// writes h as fp16 (C2) and per-head attention scores s_src/s_dst (fp32, from fp32 acc).
// One column-block (blockIdx.y) == one head (128 cols).
__launch_bounds__(256)
__global__ void k_gemm_mfma(const float* __restrict__ A, const u16* __restrict__ bthi,
                            const u16* __restrict__ btlo, _Float16* __restrict__ C2,
                            float* __restrict__ sSg, float* __restrict__ sDg,
                            const float* __restrict__ asr, const float* __restrict__ adr,
                            int M, int K, int Nc) {
    __shared__ u16 Ah[4096], Al[4096], Bh[4096], Bl[4096];   // each [4][128][8]
    __shared__ float rS[128], rD[128];
    const int t    = threadIdx.x;
    const int lane = t & 63, wv = t >> 6;
    const int wr = wv >> 1, wc = wv & 1;         // wave quadrant (2x2 of 64x64)
    const int lr = lane & 15, kq = lane >> 4;
    const int r0 = blockIdx.x * 128, c0 = blockIdx.y * 128;
    const int KS = K >> 5;
    const int H = Nc >> 7;
    const int head = blockIdx.y;

    // A staging role: thread -> (row 0..127, 16-float half)
    const int ar = t >> 1;
    const int ahf = t & 1;
    const int garow = r0 + ar;
    const bool avalid = garow < M;
    const float* arow = A + (size_t)garow * K + ahf * 16;

    const size_t bchunk0 = (size_t)blockIdx.y * KS * 4096;

    f32x4 acc[4][4];
    #pragma unroll
    for (int m = 0; m < 4; ++m)
        #pragma unroll
        for (int n = 0; n < 4; ++n) {
            acc[m][n][0] = 0.f; acc[m][n][1] = 0.f;
            acc[m][n][2] = 0.f; acc[m][n][3] = 0.f;
        }

    for (int ks = 0; ks < KS; ++ks) {
        // ---- issue A global loads (overlaps prior MFMA)
        float4 av[4];
        const float4* ap = (const float4*)(arow + ks * 32);
        if (avalid) {
            av[0] = ap[0]; av[1] = ap[1]; av[2] = ap[2]; av[3] = ap[3];
        } else {
            av[0] = av[1] = av[2] = av[3] = make_float4(0.f, 0.f, 0.f, 0.f);
        }
        __syncthreads();   // previous iteration's LDS reads complete

        // ---- split + ds_write A into [4][128][8]
        float f[16];
        f[0]=av[0].x; f[1]=av[0].y; f[2]=av[0].z; f[3]=av[0].w;
        f[4]=av[1].x; f[5]=av[1].y; f[6]=av[1].z; f[7]=av[1].w;
        f[8]=av[2].x; f[9]=av[2].y; f[10]=av[2].z; f[11]=av[2].w;
        f[12]=av[3].x; f[13]=av[3].y; f[14]=av[3].z; f[15]=av[3].w;
        u16 hi[16], lo[16];
        #pragma unroll
        for (int i = 0; i < 16; ++i) {
            hi[i] = bf16hi(f[i]);
            lo[i] = bf16hi(f[i] - bf2f(hi[i]));
        }
        #pragma unroll
        for (int q = 0; q < 2; ++q) {
            int kqi = ahf * 2 + q;
            int off = kqi * 1024 + ar * 8;
            int4 wh, wl;
            wh.x = (unsigned)hi[q*8+0] | ((unsigned)hi[q*8+1] << 16);
            wh.y = (unsigned)hi[q*8+2] | ((unsigned)hi[q*8+3] << 16);
            wh.z = (unsigned)hi[q*8+4] | ((unsigned)hi[q*8+5] << 16);
            wh.w = (unsigned)hi[q*8+6] | ((unsigned)hi[q*8+7] << 16);
            wl.x = (unsigned)lo[q*8+0] | ((unsigned)lo[q*8+1] << 16);
            wl.y = (unsigned)lo[q*8+2] | ((unsigned)lo[q*8+3] << 16);
            wl.z = (unsigned)lo[q*8+4] | ((unsigned)lo[q*8+5] << 16);
            wl.w = (unsigned)lo[q*8+6] | ((unsigned)lo[q*8+7] << 16);
            *(int4*)&Ah[off] = wh;
            *(int4*)&Al[off] = wl;
        }

        // ---- B via global_load_lds (linear; global layout pre-swizzled)
        const u16* bhs = bthi + bchunk0 + (size_t)ks * 4096;
        const u16* bls = btlo + bchunk0 + (size_t)ks * 4096;
        #pragma unroll
        for (int p = 0; p < 2; ++p) {
            int ge = p * 2048 + wv * 512 + lane * 8;   // per-lane global elem
            int le = p * 2048 + wv * 512;              // wave-uniform LDS elem
            gld_lds16(bhs + ge, &Bh[le]);
            gld_lds16(bls + ge, &Bl[le]);
        }
        __syncthreads();   // ds_writes visible + gload_lds drained

        // ---- fragments + 48 MFMAs
        short8 afh[4], afl[4], bfh[4], bfl[4];
        #pragma unroll
        for (int m = 0; m < 4; ++m) {
            int row = wr * 64 + m * 16 + lr;
            int off = kq * 1024 + row * 8;
            afh[m] = *(const short8*)&Ah[off];
            afl[m] = *(const short8*)&Al[off];
        }
        #pragma unroll
        for (int n = 0; n < 4; ++n) {
            int col = wc * 64 + n * 16 + lr;
            int off = kq * 1024 + col * 8;
            bfh[n] = *(const short8*)&Bh[off];
            bfl[n] = *(const short8*)&Bl[off];
        }
        #pragma unroll
        for (int m = 0; m < 4; ++m)
            #pragma unroll
            for (int n = 0; n < 4; ++n) {
                acc[m][n] = __builtin_amdgcn_mfma_f32_16x16x32_bf16(afh[m], bfh[n], acc[m][n], 0, 0, 0);
                acc[m][n] = __builtin_amdgcn_mfma_f32_16x16x32_bf16(afh[m], bfl[n], acc[m][n], 0, 0, 0);
                acc[m][n] = __builtin_amdgcn_mfma_f32_16x16x32_bf16(afl[m], bfh[n], acc[m][n], 0, 0, 0);
            }
    }

    // ---- epilogue A: attention-score dot products from fp32 accumulators
    float aS[4], aD[4];
    #pragma unroll
    for (int n = 0; n < 4; ++n) {
        int c = c0 + wc * 64 + n * 16 + lr;
        aS[n] = asr[c];
        aD[n] = adr[c];
    }
    __syncthreads();
    if (t < 128) { rS[t] = 0.f; rD[t] = 0.f; }
    __syncthreads();
    #pragma unroll
    for (int m = 0; m < 4; ++m) {
        #pragma unroll
        for (int j = 0; j < 4; ++j) {
            float ps = 0.f, pd = 0.f;
            #pragma unroll
            for (int n = 0; n < 4; ++n) {
                float v = acc[m][n][j];
                ps += v * aS[n];
                pd += v * aD[n];
            }
            #pragma unroll
            for (int off = 1; off < 16; off <<= 1) {
                ps += __shfl_xor(ps, off, 64);
                pd += __shfl_xor(pd, off, 64);
            }
            if (lr == 0) {
                int row = wr * 64 + m * 16 + kq * 4 + j;
                atomicAdd(&rS[row], ps);
                atomicAdd(&rD[row], pd);
            }
        }
    }
    __syncthreads();
    if (t < 128) {
        int r = r0 + t;
        if (r < M) {
            sSg[(size_t)r * H + head] = rS[t];
            sDg[(size_t)r * H + head] = rD[t];
        }
    }

    // ---- epilogue B: h -> fp16, C[row][col], col=lane&15, row=(lane>>4)*4+reg
    #pragma unroll
    for (int m = 0; m < 4; ++m) {
        int rowb = r0 + wr * 64 + m * 16 + kq * 4;
        #pragma unroll
        for (int n = 0; n < 4; ++n) {
            int col = c0 + wc * 64 + n * 16 + lr;
            #pragma unroll
            for (int j = 0; j < 4; ++j) {
                int r = rowb + j;
                if (r < M) C2[(size_t)r * Nc + col] = (_Float16)acc[m][n][j];
            }
        }
    }
}

// ---------------------------------------------------------------- per-dst softmax over incoming edges
template<int H>
__global__ void k_attn(const float* __restrict__ s_src, const float* __restrict__ s_dst,
                       const int* __restrict__ row_start, const int* __restrict__ csr,
                       float* __restrict__ alpha) {
    int n = blockIdx.x;
    int lane = threadIdx.x;           // 64
    const int EPI = 64 / H;
    int head = lane % H;
    int eo   = lane / H;
    int lo = row_start[n], hi = row_start[n + 1];
    float sd = s_dst[n * H + head];

    float mx = -INFINITY;
    for (int p = lo + eo; p < hi; p += EPI) {
        int s = csr[p];
        float e = lrelu(s_src[s * H + head] + sd);
        alpha[(size_t)p * H + head] = e;
        mx = fmaxf(mx, e);
    }
    #pragma unroll
    for (int off = H; off < 64; off <<= 1) mx = fmaxf(mx, __shfl_xor(mx, off, 64));

    float sum = 0.f;
    for (int p = lo + eo; p < hi; p += EPI) {
        float ex = expf(alpha[(size_t)p * H + head] - mx);
        alpha[(size_t)p * H + head] = ex;
        sum += ex;
    }
    #pragma unroll
    for (int off = H; off < 64; off <<= 1) sum += __shfl_xor(sum, off, 64);

    float inv = 1.f / sum;
    for (int p = lo + eo; p < hi; p += EPI) alpha[(size_t)p * H + head] *= inv;
}

// ---------------------------------------------------------------- aggregation (fp16 h rows):
// out[n] = sum_p alpha[p] * h[src[p]] + bias.  W/2 threads; thread t owns cols {2t,2t+1}.
template<int H>
__global__ void k_agg2(const _Float16* __restrict__ hb2, const float* __restrict__ alpha,
                       const int* __restrict__ row_start, const int* __restrict__ csr,
                       const float* __restrict__ bias, float* __restrict__ out) {
    const int W = H * 128;
    int n = blockIdx.x;
    int t = threadIdx.x;              // W/2 threads
    int head = t >> 6;                // col pair (2t,2t+1) -> head
    int lo = row_start[n], hi = row_start[n + 1];
    float a0 = 0.f, a1 = 0.f;
    int p = lo;
    for (; p + 2 <= hi; p += 2) {
        int s0 = csr[p], s1 = csr[p + 1];
        float al0 = alpha[(size_t)p * H + head];
        float al1 = alpha[(size_t)(p + 1) * H + head];
        unsigned u0 = *(const unsigned*)&hb2[(size_t)s0 * W + 2 * t];
        unsigned u1 = *(const unsigned*)&hb2[(size_t)s1 * W + 2 * t];
        float2 h0 = h2f2(u0), h1 = h2f2(u1);
        a0 += al0 * h0.x + al1 * h1.x;
        a1 += al0 * h0.y + al1 * h1.y;
    }
    if (p < hi) {
        int s0 = csr[p];
        float al0 = alpha[(size_t)p * H + head];
        float2 h0 = h2f2(*(const unsigned*)&hb2[(size_t)s0 * W + 2 * t]);
        a0 += al0 * h0.x;
        a1 += al0 * h0.y;
    }
    out[(size_t)n * W + 2 * t]     = a0 + bias[2 * t];
    out[(size_t)n * W + 2 * t + 1] = a1 + bias[2 * t + 1];
}

// ---------------------------------------------------------------- BatchNorm stats + apply+ELU
__global__ void k_bnstat(const float* __restrict__ x, float* __restrict__ bnsum,
                         float* __restrict__ bnsq, int W) {
    const int RPB = 64;
    int f  = threadIdx.x;             // W threads
    int r0 = blockIdx.x * RPB;
    int r1 = min(r0 + RPB, N_NODES);
    float s = 0.f, q = 0.f;
    for (int r = r0; r < r1; ++r) {
        float v = x[(size_t)r * W + f];
        s += v; q += v * v;
    }
    atomicAdd(&bnsum[f], s);
    atomicAdd(&bnsq[f], q);
}

__global__ void k_bnelu(float* __restrict__ x, const float* __restrict__ bnsum,
                        const float* __restrict__ bnsq, const float* __restrict__ gamma,
                        const float* __restrict__ beta, int W) {
    size_t total = (size_t)N_NODES * W;
    size_t i = (size_t)blockIdx.x * blockDim.x + threadIdx.x;
    if (i >= total) return;
    int f = (int)(i & (W - 1));       // W is 512 or 128 (pow2)
    const float invN = 1.f / (float)N_NODES;
    float mean = bnsum[f] * invN;
    float var  = bnsq[f] * invN - mean * mean;
    float y = gamma[f] * (x[i] - mean) * rsqrtf(var + BN_EPS) + beta[f];
    x[i] = y > 0.f ? y : expm1f(y);
}

// ---------------------------------------------------------------- global mean pool (batch_idx sorted)
__global__ void k_pool(const float* __restrict__ x, const int* __restrict__ batch,
                       float* __restrict__ out) {
    int g = blockIdx.x;               // 256
    int f = threadIdx.x;              // 128
    int a = 0, b = N_NODES;
    while (a < b) { int m = (a + b) >> 1; if (batch[m] < g) a = m + 1; else b = m; }
    int lo = a;
    b = N_NODES;
    while (a < b) { int m = (a + b) >> 1; if (batch[m] < g + 1) a = m + 1; else b = m; }
    int hi = a;
    float s = 0.f;
    for (int r = lo; r < hi; ++r) s += x[(size_t)r * 128 + f];
    int cnt = hi - lo;
    out[g * 128 + f] = s / (float)(cnt > 0 ? cnt : 1);
}

// ---------------------------------------------------------------- launch
extern "C" void kernel_launch(void* const* d_in, const int* in_sizes, int n_in,
                              void* d_out, int out_size, void* d_ws, size_t ws_size,
                              hipStream_t stream) {
    const float* x     = (const float*)d_in[0];
    const int*   ei    = (const int*)d_in[1];
    const int*   batch = (const int*)d_in[2];
    const float* Wm[3]  = {(const float*)d_in[3],  (const float*)d_in[9],  (const float*)d_in[15]};
    const float* asr[3] = {(const float*)d_in[4],  (const float*)d_in[10], (const float*)d_in[16]};
    const float* adr[3] = {(const float*)d_in[5],  (const float*)d_in[11], (const float*)d_in[17]};
    const float* bia[3] = {(const float*)d_in[6],  (const float*)d_in[12], (const float*)d_in[18]};
    const float* gam[3] = {(const float*)d_in[7],  (const float*)d_in[13], (const float*)d_in[19]};
    const float* bet[3] = {(const float*)d_in[8],  (const float*)d_in[14], (const float*)d_in[20]};

    char* w = (char*)d_ws;
    auto alloc = [&](size_t bytes) -> void* {
        void* p = (void*)w;
        w += (bytes + 255) & ~(size_t)255;
        return p;
    };
    float*     act = (float*)alloc((size_t)N_NODES * 512 * 4);
    _Float16*  hb2 = (_Float16*)alloc((size_t)N_NODES * 512 * 2);
    float*   alpha = (float*)alloc((size_t)EP * 4 * 4);
    int* csr_src   = (int*)alloc((size_t)EP * 4);
    int* row_start = (int*)alloc((size_t)(N_NODES + 1) * 4);
    int* deg       = (int*)alloc((size_t)N_NODES * 4);
    int* cursor    = (int*)alloc((size_t)N_NODES * 4);
    float* s_src = (float*)alloc((size_t)N_NODES * 4 * 4);
    float* s_dst = (float*)alloc((size_t)N_NODES * 4 * 4);
    float* bn    = (float*)alloc(1024 * 4);      // bnsum[512] + bnsq[512]
    int* totals  = (int*)alloc(64 * 4);
    u16* bthi = (u16*)alloc((size_t)512 * 512 * 2);
    u16* btlo = (u16*)alloc((size_t)512 * 512 * 2);

    // ---- CSR by dst (shared by all 3 layers)
    hipMemsetAsync(deg, 0, (size_t)N_NODES * 4, stream);
    hipMemsetAsync(cursor, 0, (size_t)N_NODES * 4, stream);
    k_hist<<<512, 256, 0, stream>>>(ei, deg);
    k_scan1<<<(N_NODES + 1023) / 1024, 1024, 0, stream>>>(deg, row_start, totals);
    k_scan2<<<1, 64, 0, stream>>>(totals, (N_NODES + 1023) / 1024);
    k_scan3<<<(N_NODES + 255) / 256, 256, 0, stream>>>(row_start, totals);
    k_scatter<<<512, 256, 0, stream>>>(ei, row_start, cursor, csr_src);

    auto layer = [&](const float* Ain, int K, int li, int H) {
        int Wd = H * 128;
        int nsh = (Wd == 512) ? 9 : 7;
        int tot = K * Wd;
        k_cvtW<<<(tot + 255) / 256, 256, 0, stream>>>(Wm[li], bthi, btlo, Wd, nsh, K >> 5);
        dim3 gg((N_NODES + 127) / 128, Wd / 128);
        k_gemm_mfma<<<gg, 256, 0, stream>>>(Ain, bthi, btlo, hb2, s_src, s_dst,
                                            asr[li], adr[li], N_NODES, K, Wd);
        if (H == 4) {
            k_attn<4><<<N_NODES, 64, 0, stream>>>(s_src, s_dst, row_start, csr_src, alpha);
            k_agg2<4><<<N_NODES, 256, 0, stream>>>(hb2, alpha, row_start, csr_src, bia[li], act);
        } else {
            k_attn<1><<<N_NODES, 64, 0, stream>>>(s_src, s_dst, row_start, csr_src, alpha);
            k_agg2<1><<<N_NODES, 64, 0, stream>>>(hb2, alpha, row_start, csr_src, bia[li], act);
        }
        hipMemsetAsync(bn, 0, 1024 * 4, stream);
        k_bnstat<<<(N_NODES + 63) / 64, Wd, 0, stream>>>(act, bn, bn + 512, Wd);
        size_t tot2 = (size_t)N_NODES * Wd;
        k_bnelu<<<(unsigned)((tot2 + 255) / 256), 256, 0, stream>>>(act, bn, bn + 512,
                                                                    gam[li], bet[li], Wd);
    };

    layer(x,   128, 0, 4);   // in -> act [N,512]
    layer(act, 512, 1, 4);   // act -> act [N,512]
    layer(act, 512, 2, 1);   // act -> act [N,128]

    k_pool<<<G_GRAPHS, 128, 0, stream>>>(act, batch, (float*)d_out);
}